// Round 9
// baseline (280.594 us; speedup 1.0000x reference)
//
#include <hip/hip_runtime.h>

// TAM fused kernel round 9: R6 block-per-sample structure, but phases 2-4 are
// WAVE-REDUNDANT (each wave computes the full coefficient chain in private
// LDS scratch) -> only ONE block-wide barrier per sample (post-staging,
// lgkm-only). Waves drift independently; no 256-thread lockstep through the
// tiny branch phases. sx4 c-rows padded to 71 f4 (c-boundary conflicts ->
// <=2-way = free). NT stores (R6 win), plain loads (L3 retention).
// C=12, T=10, H*W=28, K=3.

#define CC 12
#define TT 10
#define SAMPLE 3360
#define SAMPLE4 840
#define CROW 71              // padded f4 stride per channel (70 data + 1 pad)
#define EPSF 1e-5f

typedef float f4 __attribute__((ext_vector_type(4)));

#define FENCE() __builtin_amdgcn_sched_barrier(0)
// Wave-local LDS producer->consumer sync (single wave, lockstep lanes).
#define WSYNC() do { asm volatile("s_waitcnt lgkmcnt(0)" ::: "memory"); FENCE(); } while (0)
// Block barrier, LDS-visibility only (never forces vmcnt(0) beyond what the
// ds_writes already consumed).
#define BLOCK_SYNC() do { asm volatile("s_waitcnt lgkmcnt(0)" ::: "memory"); \
    FENCE(); __builtin_amdgcn_s_barrier(); FENCE(); } while (0)

// per-wave scratch layout (floats), 426 total:
//   pool @ 0   [120]   (live ph2->ph3; overlaid by sact in ph4)
//   sz   @ 120 [240]   (live ph3->ph4)
//   sa1  @ 360 [30]    (live ph3->ph4)
//   skern@ 390 [36]    (k0[12] k1[12] k2[12], live ph4->apply)
//   sact = pool region [0,120) (live ph4->apply)
#define SCR 426

__global__ __launch_bounds__(256) void tam_kernel(
    const float* __restrict__ x,
    const float* __restrict__ w_g1,
    const float* __restrict__ g1_gamma, const float* __restrict__ g1_beta,
    const float* __restrict__ g1_mean,  const float* __restrict__ g1_var,
    const float* __restrict__ w_g2,
    const float* __restrict__ w_l1,
    const float* __restrict__ l1_gamma, const float* __restrict__ l1_beta,
    const float* __restrict__ l1_mean,  const float* __restrict__ l1_var,
    const float* __restrict__ w_l2,
    float* __restrict__ out)
{
    __shared__ f4    sx4[CC * CROW];     // 852 f4, padded [c][70+1]
    __shared__ float wg1s[200], wg2s[60], wl1s[108], wl2s[36];
    __shared__ float gs[20], gb[20], lsc[3], lbi[3];
    __shared__ float wscr[4][SCR];

    const int n    = blockIdx.x;
    const int tid  = threadIdx.x;
    const int wid  = tid >> 6;
    const int lane = tid & 63;
    float* p = wscr[wid];

    // ---- phase 1: stage sample (coalesced 1KB bursts) + weights + BN fold ----
    const f4* xg = reinterpret_cast<const f4*>(x + (size_t)n * SAMPLE);
    f4 r[4];
    #pragma unroll
    for (int k = 0; k < 4; ++k) {
        const int v = tid + k * 256;
        if (v < SAMPLE4) r[k] = xg[v];
    }
    for (int i = tid; i < 200; i += 256) wg1s[i] = w_g1[i];
    if (tid < 60)  wg2s[tid] = w_g2[tid];
    if (tid < 108) wl1s[tid] = w_l1[tid];
    if (tid < 36)  wl2s[tid] = w_l2[tid];
    if (tid < 20) {
        const float s = rsqrtf(g1_var[tid] + EPSF) * g1_gamma[tid];
        gs[tid] = s; gb[tid] = g1_beta[tid] - g1_mean[tid] * s;
    } else if (tid < 23) {
        const int m = tid - 20;
        const float s = rsqrtf(l1_var[m] + EPSF) * l1_gamma[m];
        lsc[m] = s; lbi[m] = l1_beta[m] - l1_mean[m] * s;
    }
    #pragma unroll
    for (int k = 0; k < 4; ++k) {
        const int v = tid + k * 256;
        if (v < SAMPLE4) {
            const int c = v / 70, rm = v % 70;
            sx4[c * CROW + rm] = r[k];
        }
    }
    BLOCK_SYNC();   // the ONLY block-wide barrier per sample

    // ---- phase 2 (wave-redundant): pooling -> p[pool] ----
    #pragma unroll
    for (int q = 0; q < 2; ++q) {
        const int row = lane + q * 64;
        if (row < 120) {
            const int c = row / 10, t = row % 10;
            const f4* rp = sx4 + c * CROW + t * 7;
            f4 a = rp[0];
            #pragma unroll
            for (int i = 1; i < 7; ++i) a += rp[i];
            p[row] = (a.x + a.y + a.z + a.w) * (1.0f / 28.0f);
        }
    }
    WSYNC();

    // ---- phase 3 (wave-redundant): G hidden (0..239) + L conv1 (240..269) ----
    #pragma unroll
    for (int q = 0; q < 5; ++q) {
        const int task = lane + q * 64;
        if (task < 240) {
            const int c = task / 20, j = task % 20;
            float s = 0.f;
            #pragma unroll
            for (int t = 0; t < TT; ++t)
                s += p[c * TT + t] * wg1s[j * TT + t];
            p[120 + task] = fmaxf(gs[j] * s + gb[j], 0.f);
        } else if (task < 270) {
            const int e = task - 240;
            const int m = e / TT, t = e % TT;
            float s = 0.f;
            #pragma unroll
            for (int c = 0; c < CC; ++c) {
                #pragma unroll
                for (int k = 0; k < 3; ++k) {
                    const int t2 = t + k - 1;
                    if (t2 >= 0 && t2 < TT)
                        s += p[c * TT + t2] * wl1s[(m * CC + c) * 3 + k];
                }
            }
            p[360 + e] = fmaxf(lsc[m] * s + lbi[m], 0.f);
        }
    }
    WSYNC();

    // ---- phase 4 (wave-redundant): softmax (12) + conv2+sigmoid (120) ----
    // sact overlays the pool region p[0,120) -- pool is dead here.
    #pragma unroll
    for (int q = 0; q < 3; ++q) {
        const int task = lane + q * 64;
        if (task < CC) {
            const int c = task;
            float sc0 = 0.f, sc1 = 0.f, sc2 = 0.f;
            #pragma unroll
            for (int j = 0; j < 20; ++j) {
                const float zj = p[120 + c * 20 + j];
                sc0 += zj * wg2s[j];
                sc1 += zj * wg2s[20 + j];
                sc2 += zj * wg2s[40 + j];
            }
            const float mx = fmaxf(sc0, fmaxf(sc1, sc2));
            const float e0 = __expf(sc0 - mx), e1 = __expf(sc1 - mx), e2 = __expf(sc2 - mx);
            const float ri = 1.0f / (e0 + e1 + e2);
            p[390 + c]      = e0 * ri;
            p[402 + c]      = e1 * ri;
            p[414 + c]      = e2 * ri;
        } else if (task < 12 + 120) {
            const int e = task - 12;
            const int c = e / TT, t = e % TT;
            float s = 0.f;
            #pragma unroll
            for (int m = 0; m < 3; ++m) s += p[360 + m * TT + t] * wl2s[c * 3 + m];
            p[e] = 1.0f / (1.0f + __expf(-s));   // sact
        }
    }
    WSYNC();

    // ---- phase 5: apply, partitioned across waves by tid; NT stores ----
    // out f4 vo = t*84 + c*7 + s4 ; taps at sx4 f4 = c*CROW + t'*7 + s4.
    f4* og = reinterpret_cast<f4*>(out + (size_t)n * SAMPLE);
    #pragma unroll
    for (int k = 0; k < 4; ++k) {
        const int v = tid + k * 256;
        if (v < SAMPLE4) {
            const int t   = v / 84;
            const int rem = v % 84;
            const int c   = rem / 7;
            const int s4  = rem % 7;
            const int base = c * CROW + s4;
            const float k0 = p[390 + c];
            const float k1 = p[402 + c];
            const float k2 = p[414 + c];
            f4 acc = (k1 * p[c * TT + t]) * sx4[base + t * 7];
            if (t > 0)
                acc += (k0 * p[c * TT + t - 1]) * sx4[base + (t - 1) * 7];
            if (t < TT - 1)
                acc += (k2 * p[c * TT + t + 1]) * sx4[base + (t + 1) * 7];
            __builtin_nontemporal_store(acc, og + v);
        }
    }
}

extern "C" void kernel_launch(void* const* d_in, const int* in_sizes, int n_in,
                              void* d_out, int out_size, void* d_ws, size_t ws_size,
                              hipStream_t stream) {
    (void)n_in; (void)out_size; (void)d_ws; (void)ws_size;
    const float* x        = (const float*)d_in[0];
    const float* w_g1     = (const float*)d_in[1];
    const float* g1_gamma = (const float*)d_in[2];
    const float* g1_beta  = (const float*)d_in[3];
    const float* g1_mean  = (const float*)d_in[4];
    const float* g1_var   = (const float*)d_in[5];
    const float* w_g2     = (const float*)d_in[6];
    const float* w_l1     = (const float*)d_in[7];
    const float* l1_gamma = (const float*)d_in[8];
    const float* l1_beta  = (const float*)d_in[9];
    const float* l1_mean  = (const float*)d_in[10];
    const float* l1_var   = (const float*)d_in[11];
    const float* w_l2     = (const float*)d_in[12];
    float* out = (float*)d_out;

    const int n_total = in_sizes[0] / SAMPLE;  // 32768
    tam_kernel<<<n_total, 256, 0, stream>>>(
        x, w_g1, g1_gamma, g1_beta, g1_mean, g1_var, w_g2,
        w_l1, l1_gamma, l1_beta, l1_mean, l1_var, w_l2, out);
}

// Round 10
// 191.020 us; speedup vs baseline: 1.4689x; 1.4689x over previous
//
#include <hip/hip_runtime.h>

// TAM fused kernel round 10: R6 champion (206.9us) with ONE change --
// phase-1 staging uses global_load_lds (direct HBM->LDS DMA, 16B/lane):
// deletes 210 ds_write_b128 + the VGPR round trip per block (Common-mistake
// #1: compiler never auto-emits it). Everything else identical to R6:
// block-per-sample, 4 __syncthreads, LDS-staged folded weights, NT stores,
// plain loads (L3 retention). C=12, T=10, H*W=28, K=3.

#define CC 12
#define TT 10
#define SAMPLE 3360
#define SAMPLE4 840
#define EPSF 1e-5f

typedef float f4 __attribute__((ext_vector_type(4)));

__global__ __launch_bounds__(256) void tam_kernel(
    const float* __restrict__ x,
    const float* __restrict__ w_g1,
    const float* __restrict__ g1_gamma, const float* __restrict__ g1_beta,
    const float* __restrict__ g1_mean,  const float* __restrict__ g1_var,
    const float* __restrict__ w_g2,
    const float* __restrict__ w_l1,
    const float* __restrict__ l1_gamma, const float* __restrict__ l1_beta,
    const float* __restrict__ l1_mean,  const float* __restrict__ l1_var,
    const float* __restrict__ w_l2,
    float* __restrict__ out)
{
    __shared__ f4    sx4[SAMPLE4];   // x in input order [c][t][s4]
    __shared__ float spool[120];     // pooled[c][t]
    __shared__ float sz[240];        // G hidden
    __shared__ float sa1[30];        // L hidden [m][t]
    __shared__ float skern[36];      // k0[12] k1[12] k2[12]
    __shared__ float sact[120];      // sigmoid gate [c][t]
    __shared__ float wg1s[200], wg2s[60], wl1s[108], wl2s[36];
    __shared__ float gs[20], gb[20], lsc[3], lbi[3];

    const int n    = blockIdx.x;
    const int tid  = threadIdx.x;
    const int wid  = tid >> 6;
    const int lane = tid & 63;

    // ---- phase 1: stage sample via direct global->LDS DMA ----
    // 13 full-wave chunks of 64 f4 (1KB each), round-robin across 4 waves.
    // LDS dest is wave-uniform base + lane*16 (linear layout matches).
    const f4* xg = reinterpret_cast<const f4*>(x + (size_t)n * SAMPLE);
    for (int i = wid; i < 13; i += 4) {
        __builtin_amdgcn_global_load_lds(
            (const __attribute__((address_space(1))) void*)(xg + i * 64 + lane),
            (__attribute__((address_space(3))) void*)(&sx4[i * 64]),
            16, 0, 0);
    }
    if (tid < 8) sx4[832 + tid] = xg[832 + tid];   // tail 8 f4

    // weight staging + BN folding (hides under the DMA)
    for (int i = tid; i < 200; i += 256) wg1s[i] = w_g1[i];
    if (tid < 60)  wg2s[tid] = w_g2[tid];
    if (tid < 108) wl1s[tid] = w_l1[tid];
    if (tid < 36)  wl2s[tid] = w_l2[tid];
    if (tid < 20) {
        const float s = rsqrtf(g1_var[tid] + EPSF) * g1_gamma[tid];
        gs[tid] = s; gb[tid] = g1_beta[tid] - g1_mean[tid] * s;
    } else if (tid < 23) {
        const int m = tid - 20;
        const float s = rsqrtf(l1_var[m] + EPSF) * l1_gamma[m];
        lsc[m] = s; lbi[m] = l1_beta[m] - l1_mean[m] * s;
    }
    __syncthreads();

    // ---- phase 2: spatial mean -> spool[c*10+t] (120 threads, 7 f4 each) ----
    if (tid < 120) {
        const f4* rp = sx4 + tid * 7;
        f4 a = rp[0];
        #pragma unroll
        for (int i = 1; i < 7; ++i) a += rp[i];
        spool[tid] = (a.x + a.y + a.z + a.w) * (1.0f / 28.0f);
    }
    __syncthreads();

    // ---- phase 3: G hidden (tasks 0..239) + L conv1 (tasks 240..269) ----
    for (int task = tid; task < 270; task += 256) {
        if (task < 240) {
            const int c = task / 20, j = task % 20;
            float s = 0.f;
            #pragma unroll
            for (int t = 0; t < TT; ++t)
                s += spool[c * TT + t] * wg1s[j * TT + t];
            sz[task] = fmaxf(gs[j] * s + gb[j], 0.f);
        } else {
            const int e = task - 240;
            const int m = e / TT, t = e % TT;
            float s = 0.f;
            #pragma unroll
            for (int c = 0; c < CC; ++c) {
                #pragma unroll
                for (int k = 0; k < 3; ++k) {
                    const int t2 = t + k - 1;
                    if (t2 >= 0 && t2 < TT)
                        s += spool[c * TT + t2] * wl1s[(m * CC + c) * 3 + k];
                }
            }
            sa1[e] = fmaxf(lsc[m] * s + lbi[m], 0.f);
        }
    }
    __syncthreads();

    // ---- phase 4: G softmax (wave 0) + L conv2+sigmoid (waves 1-2) ----
    if (tid < CC) {
        const int c = tid;
        float sc0 = 0.f, sc1 = 0.f, sc2 = 0.f;
        #pragma unroll
        for (int j = 0; j < 20; ++j) {
            const float zj = sz[c * 20 + j];
            sc0 += zj * wg2s[j];
            sc1 += zj * wg2s[20 + j];
            sc2 += zj * wg2s[40 + j];
        }
        const float mx = fmaxf(sc0, fmaxf(sc1, sc2));
        const float e0 = __expf(sc0 - mx), e1 = __expf(sc1 - mx), e2 = __expf(sc2 - mx);
        const float ri = 1.0f / (e0 + e1 + e2);
        skern[c]      = e0 * ri;
        skern[12 + c] = e1 * ri;
        skern[24 + c] = e2 * ri;
    }
    if (tid >= 64 && tid < 64 + 120) {
        const int idx = tid - 64;
        const int c = idx / TT, t = idx % TT;
        float s = 0.f;
        #pragma unroll
        for (int m = 0; m < 3; ++m) s += sa1[m * TT + t] * wl2s[c * 3 + m];
        sact[idx] = 1.0f / (1.0f + __expf(-s));
    }
    __syncthreads();

    // ---- phase 5: gated temporal conv, transposed coalesced NT store ----
    // out f4 vo = t*84 + c*7 + s4 ; taps at sx4 f4 = c*70 + t'*7 + s4.
    f4* og = reinterpret_cast<f4*>(out + (size_t)n * SAMPLE);
    for (int v = tid; v < SAMPLE4; v += 256) {
        const int t   = v / 84;
        const int rem = v % 84;
        const int c   = rem / 7;
        const int s4  = rem % 7;
        const int base = c * 70 + s4;
        const float k0 = skern[c];
        const float k1 = skern[12 + c];
        const float k2 = skern[24 + c];
        f4 acc = (k1 * sact[c * TT + t]) * sx4[base + t * 7];
        if (t > 0)
            acc += (k0 * sact[c * TT + t - 1]) * sx4[base + (t - 1) * 7];
        if (t < TT - 1)
            acc += (k2 * sact[c * TT + t + 1]) * sx4[base + (t + 1) * 7];
        __builtin_nontemporal_store(acc, og + v);
    }
}

extern "C" void kernel_launch(void* const* d_in, const int* in_sizes, int n_in,
                              void* d_out, int out_size, void* d_ws, size_t ws_size,
                              hipStream_t stream) {
    (void)n_in; (void)out_size; (void)d_ws; (void)ws_size;
    const float* x        = (const float*)d_in[0];
    const float* w_g1     = (const float*)d_in[1];
    const float* g1_gamma = (const float*)d_in[2];
    const float* g1_beta  = (const float*)d_in[3];
    const float* g1_mean  = (const float*)d_in[4];
    const float* g1_var   = (const float*)d_in[5];
    const float* w_g2     = (const float*)d_in[6];
    const float* w_l1     = (const float*)d_in[7];
    const float* l1_gamma = (const float*)d_in[8];
    const float* l1_beta  = (const float*)d_in[9];
    const float* l1_mean  = (const float*)d_in[10];
    const float* l1_var   = (const float*)d_in[11];
    const float* w_l2     = (const float*)d_in[12];
    float* out = (float*)d_out;

    const int n_total = in_sizes[0] / SAMPLE;  // 32768
    tam_kernel<<<n_total, 256, 0, stream>>>(
        x, w_g1, g1_gamma, g1_beta, g1_mean, g1_var, w_g2,
        w_l1, l1_gamma, l1_beta, l1_mean, l1_var, w_l2, out);
}